// Round 6
// baseline (279.792 us; speedup 1.0000x reference)
//
#include <hip/hip_runtime.h>
#include <hip/hip_bf16.h>

#define B_  8
#define C_  256
#define CI_ 128
#define N_  4096

typedef __bf16 bf16;
typedef __attribute__((ext_vector_type(8))) __bf16 bf16x8;
typedef __attribute__((ext_vector_type(4))) __bf16 bf16x4;
typedef __attribute__((ext_vector_type(4))) float  floatx4;

static_assert(sizeof(bf16) == 2, "bf16 size");

__device__ inline floatx4 mfma16(bf16x8 a, bf16x8 b, floatx4 c) {
    return __builtin_amdgcn_mfma_f32_16x16x32_bf16(a, b, c, 0, 0, 0);
}

// ---------------------------------------------------------------------------
// Runtime dtype detection (inputs measured fp32; probe kept for robustness).
// ---------------------------------------------------------------------------
__device__ inline bool detect_fp32(const void* probe) {
    const unsigned short* u = (const unsigned short*)probe;
    int lane = threadIdx.x & 63;
    unsigned short w = u[lane * 2];
    int ex = (w >> 7) & 0xFF;
    bool insane = !((ex > 96 && ex < 143) || (w & 0x7FFF) == 0);
    unsigned long long b = __ballot(insane);
    return __popcll(b) > 16;
}

__device__ inline bf16x8 load8(const void* p, size_t i, bool fp32) {
    if (!fp32) return *(const bf16x8*)((const bf16*)p + i);
    const float* f = (const float*)p + i;
    floatx4 a = *(const floatx4*)(f);
    floatx4 c = *(const floatx4*)(f + 4);
    bf16x8 r;
    r[0] = (bf16)a[0]; r[1] = (bf16)a[1]; r[2] = (bf16)a[2]; r[3] = (bf16)a[3];
    r[4] = (bf16)c[0]; r[5] = (bf16)c[1]; r[6] = (bf16)c[2]; r[7] = (bf16)c[3];
    return r;
}

__device__ inline float loadv(const void* p, size_t i, bool fp32) {
    return fp32 ? ((const float*)p)[i] : (float)((const bf16*)p)[i];
}

__device__ inline bf16x8 cvt8(floatx4 a, floatx4 b) {
    bf16x8 r;
    r[0] = (bf16)a[0]; r[1] = (bf16)a[1]; r[2] = (bf16)a[2]; r[3] = (bf16)a[3];
    r[4] = (bf16)b[0]; r[5] = (bf16)b[1]; r[6] = (bf16)b[2]; r[7] = (bf16)b[3];
    return r;
}

// ---------------------------------------------------------------------------
// FUSED kernel: proj (phase A) + grid barrier + attention/final (phase B).
//   Grid 256 = 1 block/CU (forced by 143 KB LDS), all blocks co-resident,
//   so a device-scope atomic barrier is safe (guide §1/§6 G16).
// Phase A = round-4-verified proj3 k-loop for this block's 128-px tile.
//   T-tile never leaves the block: parked in LDS (Tl), consumed as qf.
//   P/G bounce through LDS then stream out COALESCED (32 KB contiguous /
//   256-B rows) replacing 96 scalar 2-B scattered stores per lane.
// Barrier: memsetAsync-zeroed counter; __threadfence release + agent-scope
//   acquire spin (cross-XCD visibility per CDNA4 memory model).
// Phase B = round-2/3-verified attn (j-split, fused W GEMM + residual),
//   qf from Tl instead of global T; K=P / V=G read from just-written ws.
// LDS map (byte offsets in smem[143360]):
//   phase A: xT@0 [128][40], wl@10240 [384][40], Pl@40960 [128][128],
//            Gl@73728 [128][128], Tl@108544 [128][136]
//   phase B: Kl/Vt@g*35840 (<71680), Pw@71680, scrO@0, scrL@71680,
//            Wl@0, Yl@108544 (overlays Tl — dead after qf load)
// ---------------------------------------------------------------------------
__global__ __launch_bounds__(512) void fused_kernel(
    const void* __restrict__ x,
    const void* __restrict__ th_w, const void* __restrict__ th_b,
    const void* __restrict__ ph_w, const void* __restrict__ ph_b,
    const void* __restrict__ g_w,  const void* __restrict__ g_b,
    const void* __restrict__ Ww,   const void* __restrict__ Wb,
    bf16* __restrict__ Pg,         // [B][N][CI] workspace (K)
    bf16* __restrict__ Gg,         // [B][CI][N] workspace (V)
    unsigned* __restrict__ cnt,    // grid-barrier counter (memset to 0)
    void* __restrict__ out)
{
    const int bid = blockIdx.x;
    const int b   = bid & 7;            // XCD-aligned under %8 dispatch
    const int i0  = (bid >> 3) * 128;

    __shared__ __align__(16) char smem[143360];

    const bool fp32 = detect_fp32(x);

    const int t    = threadIdx.x;
    const int w    = t >> 6;            // 0..7
    const int lane = t & 63;
    const int l15  = lane & 15;
    const int quad = lane >> 4;

    bf16* Tl = (bf16*)(smem + 108544);  // [128][136] — lives until qf load

    // ===================== Phase A: projections =====================
    {
        bf16* xT = (bf16*)(smem);           // [128][40]
        bf16* wl = (bf16*)(smem + 10240);   // [384][40]
        bf16* Pl = (bf16*)(smem + 40960);   // [128][128]
        bf16* Gl = (bf16*)(smem + 73728);   // [128][128]

        const int wm = w >> 1;   // R 16-slice
        const int wn = w & 1;    // px half
        const int sc = t >> 4;   // staging channel 0..31
        const int sm = t & 15;   // staging px-octet
        const int wr = t >> 2;   // w-staging row 0..127
        const int wc = (t & 3) * 8;

        floatx4 acc[6][4];
#pragma unroll
        for (int f = 0; f < 6; ++f)
#pragma unroll
            for (int ni = 0; ni < 4; ++ni) acc[f][ni] = (floatx4)0.f;

        floatx4 pxa, pxb; bf16x8 pxh;
        floatx4 pwa[3], pwb[3]; bf16x8 pwh[3];

        auto issue = [&](int k) {
            size_t xo = ((size_t)b * C_ + k + sc) * N_ + i0 + sm * 8;
            if (fp32) {
                const float* fx_ = (const float*)x + xo;
                pxa = *(const floatx4*)fx_;
                pxb = *(const floatx4*)(fx_ + 4);
            } else {
                pxh = *(const bf16x8*)((const bf16*)x + xo);
            }
#pragma unroll
            for (int p = 0; p < 3; ++p) {
                const void* ws = (p == 0) ? th_w : (p == 1) ? ph_w : g_w;
                size_t wo = (size_t)wr * C_ + k + wc;
                if (fp32) {
                    const float* fw_ = (const float*)ws + wo;
                    pwa[p] = *(const floatx4*)fw_;
                    pwb[p] = *(const floatx4*)(fw_ + 4);
                } else {
                    pwh[p] = *(const bf16x8*)((const bf16*)ws + wo);
                }
            }
        };

        issue(0);

        for (int ks = 0; ks < 8; ++ks) {
            {
                bf16x8 xv = fp32 ? cvt8(pxa, pxb) : pxh;
                int colx = ((((sc >> 3) + sm) & 3) << 3) + (sc & 7);
#pragma unroll
                for (int i = 0; i < 8; ++i) xT[(sm * 8 + i) * 40 + colx] = xv[i];
#pragma unroll
                for (int p = 0; p < 3; ++p) {
                    bf16x8 wv = fp32 ? cvt8(pwa[p], pwb[p]) : pwh[p];
                    *(bf16x8*)(&wl[(p * 128 + wr) * 40 + wc]) = wv;
                }
            }
            __syncthreads();

            if (ks < 7) issue((ks + 1) * 32);

            bf16x8 fxr[4], fwr[6];
#pragma unroll
            for (int ni = 0; ni < 4; ++ni) {
                int px = wn * 64 + ni * 16 + l15;
                int ch = (quad + (px >> 3)) & 3;
                fxr[ni] = *(const bf16x8*)(&xT[px * 40 + ch * 8]);
            }
#pragma unroll
            for (int f = 0; f < 6; ++f)
                fwr[f] = *(const bf16x8*)(&wl[(f * 64 + wm * 16 + l15) * 40 + quad * 8]);

#pragma unroll
            for (int f = 0; f < 4; ++f)
#pragma unroll
                for (int ni = 0; ni < 4; ++ni)
                    acc[f][ni] = mfma16(fxr[ni], fwr[f], acc[f][ni]);
#pragma unroll
            for (int f = 4; f < 6; ++f)
#pragma unroll
                for (int ni = 0; ni < 4; ++ni)
                    acc[f][ni] = mfma16(fwr[f], fxr[ni], acc[f][ni]);

            __syncthreads();
        }

        // ---- epilogue: bias + park in LDS (T->Tl, P->Pl, G->Gl) ----
#pragma unroll
        for (int f = 0; f < 6; ++f) {
            if (f < 4) {
                int o = (f & 1) * 64 + wm * 16 + l15;
                float bv = loadv((f < 2) ? th_b : ph_b, o, fp32);
                bf16* dst   = (f < 2) ? Tl : Pl;
                int   strd  = (f < 2) ? 136 : 128;
#pragma unroll
                for (int ni = 0; ni < 4; ++ni)
#pragma unroll
                    for (int r = 0; r < 4; ++r) {
                        int pxl = wn * 64 + ni * 16 + quad * 4 + r;
                        dst[pxl * strd + o] = (bf16)(acc[f][ni][r] + bv);
                    }
            } else {
#pragma unroll
                for (int r = 0; r < 4; ++r) {
                    int o = (f & 1) * 64 + wm * 16 + quad * 4 + r;
                    float bv = loadv(g_b, o, fp32);
#pragma unroll
                    for (int ni = 0; ni < 4; ++ni) {
                        int pxl = wn * 64 + ni * 16 + l15;
                        Gl[o * 128 + pxl] = (bf16)(acc[f][ni][r] + bv);
                    }
                }
            }
        }
        __syncthreads();

        // ---- coalesced global stores: P 32KB contiguous, G 256-B rows ----
        {
            char* Pls  = smem + 40960;
            char* Gls  = smem + 73728;
            char* Pdst = (char*)(Pg + ((size_t)b * N_ + i0) * CI_);
            char* Gdst = (char*)(Gg + (size_t)b * CI_ * N_ + i0);
#pragma unroll
            for (int j = 0; j < 4; ++j) {
                int off = j * 8192 + t * 16;
                *(bf16x8*)(Pdst + off) = *(const bf16x8*)(Pls + off);
                int o  = off >> 8;
                int wi = off & 255;
                *(bf16x8*)(Gdst + (size_t)o * (N_ * 2) + wi) =
                    *(const bf16x8*)(Gls + off);
            }
        }
    }

    // qf from Tl (attn-wave mapping; both j-groups need the same q rows)
    const int g  = w >> 2;              // j-half group
    const int wg = w & 3;               // wave within group
    const int tg = t & 255;             // thread within group

    bf16x8 qf[2][4];
#pragma unroll
    for (int rf = 0; rf < 2; ++rf) {
        int row = wg * 32 + rf * 16 + l15;
#pragma unroll
        for (int ks = 0; ks < 4; ++ks)
            qf[rf][ks] = *(const bf16x8*)(&Tl[row * 136 + ks * 32 + quad * 8]);
    }

    // ===================== grid barrier =====================
    __threadfence();                     // release P/G stores device-wide
    __syncthreads();
    if (t == 0) {
        __hip_atomic_fetch_add(cnt, 1u, __ATOMIC_ACQ_REL, __HIP_MEMORY_SCOPE_AGENT);
        while (__hip_atomic_load(cnt, __ATOMIC_ACQUIRE, __HIP_MEMORY_SCOPE_AGENT) < 256u)
            __builtin_amdgcn_s_sleep(8);
    }
    __syncthreads();

    // ===================== Phase B: attention + final =====================
    bf16* Kl = (bf16*)(smem + g * 35840);           // [64][136]
    bf16* Vt = (bf16*)(smem + g * 35840 + 17408);   // [128][72]
    bf16* Pw = (bf16*)(smem + 71680 + w * 4608);    // [32][72]

    const bf16* Kb = Pg + (size_t)b * N_ * CI_;
    const bf16* Vb = Gg + (size_t)b * CI_ * N_;
    const int jbase = g * 2048;

    floatx4 O[2][8];
#pragma unroll
    for (int rf = 0; rf < 2; ++rf)
#pragma unroll
        for (int cf = 0; cf < 8; ++cf) O[rf][cf] = (floatx4)0.f;
    float lsum[2][4];
#pragma unroll
    for (int rf = 0; rf < 2; ++rf)
#pragma unroll
        for (int r = 0; r < 4; ++r) lsum[rf][r] = 0.f;

    bf16x8 kreg[4], vreg[4];
#pragma unroll
    for (int s = 0; s < 4; ++s) {
        int id = tg + s * 256;
        kreg[s] = *(const bf16x8*)(Kb + (size_t)(jbase + (id >> 4)) * CI_ + (id & 15) * 8);
        vreg[s] = *(const bf16x8*)(Vb + (size_t)(id >> 3) * N_ + jbase + (id & 7) * 8);
    }

    for (int it = 0; it < 32; ++it) {
#pragma unroll
        for (int s = 0; s < 4; ++s) {
            int id = tg + s * 256;
            *(bf16x8*)(Kl + (id >> 4) * 136 + (id & 15) * 8) = kreg[s];
            *(bf16x8*)(Vt + (id >> 3) * 72 + (id & 7) * 8) = vreg[s];
        }
        __syncthreads();

        if (it < 31) {
            int j0n = jbase + (it + 1) * 64;
#pragma unroll
            for (int s = 0; s < 4; ++s) {
                int id = tg + s * 256;
                kreg[s] = *(const bf16x8*)(Kb + (size_t)(j0n + (id >> 4)) * CI_ + (id & 15) * 8);
                vreg[s] = *(const bf16x8*)(Vb + (size_t)(id >> 3) * N_ + j0n + (id & 7) * 8);
            }
        }

        // S = Q K^T
        floatx4 S[2][4];
#pragma unroll
        for (int jf = 0; jf < 4; ++jf) {
            floatx4 s0 = (floatx4)0.f, s1 = (floatx4)0.f;
#pragma unroll
            for (int ks = 0; ks < 4; ++ks) {
                bf16x8 kf = *(const bf16x8*)(Kl + (jf * 16 + l15) * 136 + ks * 32 + quad * 8);
                s0 = mfma16(qf[0][ks], kf, s0);
                s1 = mfma16(qf[1][ks], kf, s1);
            }
            S[0][jf] = s0;
            S[1][jf] = s1;
        }

        // P = exp(S); per-lane partial l; bf16 P to per-wave LDS (A-layout)
#pragma unroll
        for (int rf = 0; rf < 2; ++rf)
#pragma unroll
            for (int r = 0; r < 4; ++r) {
                float p0 = __expf(S[rf][0][r]);
                float p1 = __expf(S[rf][1][r]);
                float p2 = __expf(S[rf][2][r]);
                float p3 = __expf(S[rf][3][r]);
                lsum[rf][r] += (p0 + p1) + (p2 + p3);
                int row = rf * 16 + quad * 4 + r;
                Pw[row * 72 + 0 * 16 + l15] = (bf16)p0;
                Pw[row * 72 + 1 * 16 + l15] = (bf16)p1;
                Pw[row * 72 + 2 * 16 + l15] = (bf16)p2;
                Pw[row * 72 + 3 * 16 + l15] = (bf16)p3;
            }

        // O += P V
#pragma unroll
        for (int ks = 0; ks < 2; ++ks) {
            bf16x8 pf0 = *(const bf16x8*)(Pw + l15 * 72 + ks * 32 + quad * 8);
            bf16x8 pf1 = *(const bf16x8*)(Pw + (16 + l15) * 72 + ks * 32 + quad * 8);
#pragma unroll
            for (int cf = 0; cf < 8; ++cf) {
                bf16x8 vf = *(const bf16x8*)(Vt + (cf * 16 + l15) * 72 + ks * 32 + quad * 8);
                O[0][cf] = mfma16(pf0, vf, O[0][cf]);
                O[1][cf] = mfma16(pf1, vf, O[1][cf]);
            }
        }
        __syncthreads();
    }

    // ---- combine group 1 partials into group 0 via stage LDS ----
    float* scrO = (float*)smem;             // [64][256] f32
    float* scrL = (float*)(smem + 71680);   // [8][256]  f32
    bf16*  Yl   = (bf16*)(smem + 108544);   // [128][136] (overlays dead Tl)
    if (g == 1) {
#pragma unroll
        for (int rf = 0; rf < 2; ++rf)
#pragma unroll
            for (int cf = 0; cf < 8; ++cf)
#pragma unroll
                for (int r = 0; r < 4; ++r)
                    scrO[(rf * 32 + cf * 4 + r) * 256 + wg * 64 + lane] = O[rf][cf][r];
#pragma unroll
        for (int rf = 0; rf < 2; ++rf)
#pragma unroll
            for (int r = 0; r < 4; ++r)
                scrL[(rf * 4 + r) * 256 + wg * 64 + lane] = lsum[rf][r];
    }
    __syncthreads();
    if (g == 0) {
#pragma unroll
        for (int rf = 0; rf < 2; ++rf)
#pragma unroll
            for (int cf = 0; cf < 8; ++cf)
#pragma unroll
                for (int r = 0; r < 4; ++r)
                    O[rf][cf][r] += scrO[(rf * 32 + cf * 4 + r) * 256 + wg * 64 + lane];

#pragma unroll
        for (int rf = 0; rf < 2; ++rf)
#pragma unroll
            for (int r = 0; r < 4; ++r) {
                float rs = lsum[rf][r] + scrL[(rf * 4 + r) * 256 + wg * 64 + lane];
                rs += __shfl_xor(rs, 1);
                rs += __shfl_xor(rs, 2);
                rs += __shfl_xor(rs, 4);
                rs += __shfl_xor(rs, 8);
                lsum[rf][r] = 1.f / rs;
            }

        // normalized bf16 Y-tile into LDS (row = px-local, col = ci)
#pragma unroll
        for (int rf = 0; rf < 2; ++rf)
#pragma unroll
            for (int cf = 0; cf < 8; ++cf)
#pragma unroll
                for (int r = 0; r < 4; ++r) {
                    int px = wg * 32 + rf * 16 + quad * 4 + r;
                    Yl[px * 136 + cf * 16 + l15] =
                        (bf16)(O[rf][cf][r] * lsum[rf][r]);
                }
    }
    __syncthreads();

    // ---- stage W_w -> Wl bf16 [256][136] over the dead staging region ----
    bf16* Wl = (bf16*)smem;
#pragma unroll
    for (int p = 0; p < 16; ++p) {
        int idx = p * 2048 + t * 4;
        int o   = idx >> 7;
        int ci  = idx & 127;
        bf16x4 v;
        if (fp32) {
            floatx4 f4 = *(const floatx4*)((const float*)Ww + idx);
            v[0] = (bf16)f4[0]; v[1] = (bf16)f4[1];
            v[2] = (bf16)f4[2]; v[3] = (bf16)f4[3];
        } else {
            v = *(const bf16x4*)((const bf16*)Ww + idx);
        }
        *(bf16x4*)(&Wl[o * 136 + ci]) = v;
    }
    __syncthreads();

    // ---- out[o][px] = Ww @ Y + Wb + x : 8 waves = 4(o) x 2(px) of 64x64 ----
    {
        const int wm = w >> 1;
        const int wn = w & 1;
        floatx4 acc[4][4];
#pragma unroll
        for (int i = 0; i < 4; ++i)
#pragma unroll
            for (int j = 0; j < 4; ++j) acc[i][j] = (floatx4)0.f;

#pragma unroll
        for (int ks = 0; ks < 4; ++ks) {
            bf16x8 fa[4], fb[4];
#pragma unroll
            for (int i = 0; i < 4; ++i) {
                fa[i] = *(const bf16x8*)(&Wl[(wm * 64 + i * 16 + l15) * 136 + ks * 32 + quad * 8]);
                fb[i] = *(const bf16x8*)(&Yl[(wn * 64 + i * 16 + l15) * 136 + ks * 32 + quad * 8]);
            }
#pragma unroll
            for (int mi = 0; mi < 4; ++mi)
#pragma unroll
                for (int ni = 0; ni < 4; ++ni)
                    acc[mi][ni] = mfma16(fa[mi], fb[ni], acc[mi][ni]);
        }

#pragma unroll
        for (int mi = 0; mi < 4; ++mi)
#pragma unroll
            for (int ni = 0; ni < 4; ++ni)
#pragma unroll
                for (int r = 0; r < 4; ++r) {
                    int oo = wm * 64 + mi * 16 + quad * 4 + r;
                    int px = i0 + wn * 64 + ni * 16 + l15;
                    size_t idx = ((size_t)b * C_ + oo) * N_ + px;
                    float v = acc[mi][ni][r] + loadv(Wb, oo, fp32)
                            + loadv(x, idx, fp32);
                    if (fp32) ((float*)out)[idx] = v;
                    else      ((bf16*)out)[idx] = (bf16)v;
                }
    }
}

// ---------------------------------------------------------------------------
extern "C" void kernel_launch(void* const* d_in, const int* in_sizes, int n_in,
                              void* d_out, int out_size, void* d_ws, size_t ws_size,
                              hipStream_t stream) {
    const void* x    = d_in[0];
    const void* g_w  = d_in[1];
    const void* g_b  = d_in[2];
    const void* th_w = d_in[3];
    const void* th_b = d_in[4];
    const void* ph_w = d_in[5];
    const void* ph_b = d_in[6];
    const void* W_w  = d_in[7];
    const void* W_b  = d_in[8];

    const size_t plane = (size_t)B_ * N_ * CI_;
    bf16* Pg = (bf16*)d_ws;
    bf16* Gg = Pg + plane;
    unsigned* cnt = (unsigned*)(Gg + plane);

    hipMemsetAsync(cnt, 0, sizeof(unsigned), stream);
    fused_kernel<<<dim3(N_ / 128 * B_), 512, 0, stream>>>(
        x, th_w, th_b, ph_w, ph_b, g_w, g_b, W_w, W_b, Pg, Gg, cnt, d_out);
}

// Round 7
// 242.962 us; speedup vs baseline: 1.1516x; 1.1516x over previous
//
#include <hip/hip_runtime.h>
#include <hip/hip_bf16.h>

#define B_  8
#define C_  256
#define CI_ 128
#define N_  4096

typedef __bf16 bf16;
typedef __attribute__((ext_vector_type(8))) __bf16 bf16x8;
typedef __attribute__((ext_vector_type(4))) __bf16 bf16x4;
typedef __attribute__((ext_vector_type(4))) float  floatx4;

static_assert(sizeof(bf16) == 2, "bf16 size");

__device__ inline floatx4 mfma16(bf16x8 a, bf16x8 b, floatx4 c) {
    return __builtin_amdgcn_mfma_f32_16x16x32_bf16(a, b, c, 0, 0, 0);
}

// ---------------------------------------------------------------------------
// Runtime dtype detection (inputs measured fp32; probe kept for robustness).
// ---------------------------------------------------------------------------
__device__ inline bool detect_fp32(const void* probe) {
    const unsigned short* u = (const unsigned short*)probe;
    int lane = threadIdx.x & 63;
    unsigned short w = u[lane * 2];
    int ex = (w >> 7) & 0xFF;
    bool insane = !((ex > 96 && ex < 143) || (w & 0x7FFF) == 0);
    unsigned long long b = __ballot(insane);
    return __popcll(b) > 16;
}

__device__ inline bf16x8 load8(const void* p, size_t i, bool fp32) {
    if (!fp32) return *(const bf16x8*)((const bf16*)p + i);
    const float* f = (const float*)p + i;
    floatx4 a = *(const floatx4*)(f);
    floatx4 c = *(const floatx4*)(f + 4);
    bf16x8 r;
    r[0] = (bf16)a[0]; r[1] = (bf16)a[1]; r[2] = (bf16)a[2]; r[3] = (bf16)a[3];
    r[4] = (bf16)c[0]; r[5] = (bf16)c[1]; r[6] = (bf16)c[2]; r[7] = (bf16)c[3];
    return r;
}

__device__ inline float loadv(const void* p, size_t i, bool fp32) {
    return fp32 ? ((const float*)p)[i] : (float)((const bf16*)p)[i];
}

__device__ inline bf16x8 cvt8(floatx4 a, floatx4 b) {
    bf16x8 r;
    r[0] = (bf16)a[0]; r[1] = (bf16)a[1]; r[2] = (bf16)a[2]; r[3] = (bf16)a[3];
    r[4] = (bf16)b[0]; r[5] = (bf16)b[1]; r[6] = (bf16)b[2]; r[7] = (bf16)b[3];
    return r;
}

// ---------------------------------------------------------------------------
// Kernel 1: three 1x1-conv projections in one block per 128-px tile.
// (Round-4 verified; round-6 attribution showed this is ~36 us, not the
// 90 us previously mis-attributed — the difference was fixed harness
// overhead. Keep as-is.)
// ---------------------------------------------------------------------------
__global__ __launch_bounds__(512) void proj3_kernel(
    const void* __restrict__ x,
    const void* __restrict__ wt, const void* __restrict__ bt,
    const void* __restrict__ wp, const void* __restrict__ bp,
    const void* __restrict__ wg, const void* __restrict__ bg,
    bf16* __restrict__ T, bf16* __restrict__ P, bf16* __restrict__ G)
{
    const bool fp32 = detect_fp32(x);

    const int b  = blockIdx.y;
    const int n0 = blockIdx.x * 128;

    __shared__ bf16 xT[128][40];
    __shared__ bf16 wl[384][40];

    const int t    = threadIdx.x;
    const int w    = t >> 6;
    const int lane = t & 63;
    const int l15  = lane & 15;
    const int quad = lane >> 4;
    const int wm   = w >> 1;     // R 16-slice within each 64-block
    const int wn   = w & 1;      // px half

    const int sc = t >> 4;       // staging channel 0..31
    const int sm = t & 15;       // staging px-octet
    const int wr = t >> 2;       // w-staging row 0..127
    const int wc = (t & 3) * 8;

    floatx4 acc[6][4];
#pragma unroll
    for (int f = 0; f < 6; ++f)
#pragma unroll
        for (int ni = 0; ni < 4; ++ni) acc[f][ni] = (floatx4)0.f;

    floatx4 pxa, pxb; bf16x8 pxh;
    floatx4 pwa[3], pwb[3]; bf16x8 pwh[3];

    auto issue = [&](int k) {
        size_t xo = ((size_t)b * C_ + k + sc) * N_ + n0 + sm * 8;
        if (fp32) {
            const float* fx_ = (const float*)x + xo;
            pxa = *(const floatx4*)fx_;
            pxb = *(const floatx4*)(fx_ + 4);
        } else {
            pxh = *(const bf16x8*)((const bf16*)x + xo);
        }
#pragma unroll
        for (int p = 0; p < 3; ++p) {
            const void* ws = (p == 0) ? wt : (p == 1) ? wp : wg;
            size_t wo = (size_t)wr * C_ + k + wc;
            if (fp32) {
                const float* fw_ = (const float*)ws + wo;
                pwa[p] = *(const floatx4*)fw_;
                pwb[p] = *(const floatx4*)(fw_ + 4);
            } else {
                pwh[p] = *(const bf16x8*)((const bf16*)ws + wo);
            }
        }
    };

    issue(0);

    for (int ks = 0; ks < 8; ++ks) {
        {
            bf16x8 xv = fp32 ? cvt8(pxa, pxb) : pxh;
            int colx = ((((sc >> 3) + sm) & 3) << 3) + (sc & 7);
#pragma unroll
            for (int i = 0; i < 8; ++i) xT[sm * 8 + i][colx] = xv[i];
#pragma unroll
            for (int p = 0; p < 3; ++p) {
                bf16x8 wv = fp32 ? cvt8(pwa[p], pwb[p]) : pwh[p];
                *(bf16x8*)(&wl[p * 128 + wr][wc]) = wv;
            }
        }
        __syncthreads();

        if (ks < 7) issue((ks + 1) * 32);

        bf16x8 fxr[4], fwr[6];
#pragma unroll
        for (int ni = 0; ni < 4; ++ni) {
            int px = wn * 64 + ni * 16 + l15;
            int ch = (quad + (px >> 3)) & 3;
            fxr[ni] = *(const bf16x8*)(&xT[px][ch * 8]);
        }
#pragma unroll
        for (int f = 0; f < 6; ++f)
            fwr[f] = *(const bf16x8*)(&wl[f * 64 + wm * 16 + l15][quad * 8]);

#pragma unroll
        for (int f = 0; f < 4; ++f)
#pragma unroll
            for (int ni = 0; ni < 4; ++ni)
                acc[f][ni] = mfma16(fxr[ni], fwr[f], acc[f][ni]);
#pragma unroll
        for (int f = 4; f < 6; ++f)
#pragma unroll
            for (int ni = 0; ni < 4; ++ni)
                acc[f][ni] = mfma16(fwr[f], fxr[ni], acc[f][ni]);

        __syncthreads();
    }

    // ---- epilogue: bias + store ----
#pragma unroll
    for (int f = 0; f < 6; ++f) {
        const void* bsel = (f < 2) ? bt : (f < 4) ? bp : bg;
        if (f < 4) {
            bf16* outp = ((f < 2) ? T : P) + (size_t)b * N_ * CI_;
            int o = (f & 1) * 64 + wm * 16 + l15;
            float bv = loadv(bsel, o, fp32);
#pragma unroll
            for (int ni = 0; ni < 4; ++ni)
#pragma unroll
                for (int r = 0; r < 4; ++r) {
                    int px = n0 + wn * 64 + ni * 16 + quad * 4 + r;
                    outp[(size_t)px * CI_ + o] = (bf16)(acc[f][ni][r] + bv);
                }
        } else {
            bf16* outp = G + (size_t)b * CI_ * N_;
#pragma unroll
            for (int r = 0; r < 4; ++r) {
                int o = (f & 1) * 64 + wm * 16 + quad * 4 + r;
                float bv = loadv(bsel, o, fp32);
#pragma unroll
                for (int ni = 0; ni < 4; ++ni) {
                    int px = n0 + wn * 64 + ni * 16 + l15;
                    outp[(size_t)o * N_ + px] = (bf16)(acc[f][ni][r] + bv);
                }
            }
        }
    }
}

// ---------------------------------------------------------------------------
// Kernel 2: flash attention v7 — round-3/4 structure (j-split + fused W GEMM
// + residual) with two surgical changes:
//   1. Pw stride 72 -> 76 bf16 (152 B = 38 dw): the P-store's four quads now
//      land on banks {0,24,16,8} instead of {0,16,0,16} — kills the 4-way
//      write conflict on 128 stores/iter/wave (bulk of 9.7M conflict cycles).
//      Read side (38*l15 mod 32, gcd 2) stays conflict-free.
//   2. s_setprio(1) around the QK and PV MFMA clusters (T5).
// LDS map: Kl/Vt @ g*35840 (<71680); Pw @ 71680 + w*4864 (ends 110592);
//   combine: scrO@0, scrL@71680 (over dead Pw), Yl@108544 (over dead Pw
//   tail), Wl@0 (after scrO reads). All overlays at phase boundaries only.
// ---------------------------------------------------------------------------
__global__ __launch_bounds__(512) void attn_kernel(
    const bf16* __restrict__ T,   // [B][N][CI]
    const bf16* __restrict__ P,   // [B][N][CI]
    const bf16* __restrict__ G,   // [B][CI][N]
    const void* __restrict__ Ww,  // [C][CI]
    const void* __restrict__ Wb,  // [C]
    const void* __restrict__ x,   // [B][C][N]
    void* __restrict__ out)       // [B][C][N]
{
    const int bid = blockIdx.x;
    const int b   = bid & 7;            // XCD-aligned under %8 dispatch
    const int i0  = (bid >> 3) * 128;

    __shared__ __align__(16) char smem[143360];

    const bool fp32 = detect_fp32(x);

    const int t    = threadIdx.x;
    const int w    = t >> 6;            // 0..7
    const int g    = w >> 2;            // j-half group
    const int wg   = w & 3;             // wave within group
    const int tg   = t & 255;           // thread within group
    const int lane = t & 63;
    const int l15  = lane & 15;
    const int quad = lane >> 4;

    bf16* Kl = (bf16*)(smem + g * 35840);           // [64][136]
    bf16* Vt = (bf16*)(smem + g * 35840 + 17408);   // [128][72]
    bf16* Pw = (bf16*)(smem + 71680 + w * 4864);    // [32][76]

    const bf16* Kb = P + (size_t)b * N_ * CI_;
    const bf16* Vb = G + (size_t)b * CI_ * N_;
    const int jbase = g * 2048;

    bf16x8 qf[2][4];
#pragma unroll
    for (int rf = 0; rf < 2; ++rf) {
        const bf16* Qb = T + ((size_t)b * N_ + i0 + wg * 32 + rf * 16 + l15) * CI_;
#pragma unroll
        for (int ks = 0; ks < 4; ++ks)
            qf[rf][ks] = *(const bf16x8*)(Qb + ks * 32 + quad * 8);
    }

    floatx4 O[2][8];
#pragma unroll
    for (int rf = 0; rf < 2; ++rf)
#pragma unroll
        for (int cf = 0; cf < 8; ++cf) O[rf][cf] = (floatx4)0.f;
    float lsum[2][4];
#pragma unroll
    for (int rf = 0; rf < 2; ++rf)
#pragma unroll
        for (int r = 0; r < 4; ++r) lsum[rf][r] = 0.f;

    bf16x8 kreg[4], vreg[4];
#pragma unroll
    for (int s = 0; s < 4; ++s) {
        int id = tg + s * 256;
        kreg[s] = *(const bf16x8*)(Kb + (size_t)(jbase + (id >> 4)) * CI_ + (id & 15) * 8);
        vreg[s] = *(const bf16x8*)(Vb + (size_t)(id >> 3) * N_ + jbase + (id & 7) * 8);
    }

    for (int it = 0; it < 32; ++it) {
#pragma unroll
        for (int s = 0; s < 4; ++s) {
            int id = tg + s * 256;
            *(bf16x8*)(Kl + (id >> 4) * 136 + (id & 15) * 8) = kreg[s];
            *(bf16x8*)(Vt + (id >> 3) * 72 + (id & 7) * 8) = vreg[s];
        }
        __syncthreads();

        if (it < 31) {
            int j0n = jbase + (it + 1) * 64;
#pragma unroll
            for (int s = 0; s < 4; ++s) {
                int id = tg + s * 256;
                kreg[s] = *(const bf16x8*)(Kb + (size_t)(j0n + (id >> 4)) * CI_ + (id & 15) * 8);
                vreg[s] = *(const bf16x8*)(Vb + (size_t)(id >> 3) * N_ + j0n + (id & 7) * 8);
            }
        }

        // S = Q K^T
        floatx4 S[2][4];
        __builtin_amdgcn_s_setprio(1);
#pragma unroll
        for (int jf = 0; jf < 4; ++jf) {
            floatx4 s0 = (floatx4)0.f, s1 = (floatx4)0.f;
#pragma unroll
            for (int ks = 0; ks < 4; ++ks) {
                bf16x8 kf = *(const bf16x8*)(Kl + (jf * 16 + l15) * 136 + ks * 32 + quad * 8);
                s0 = mfma16(qf[0][ks], kf, s0);
                s1 = mfma16(qf[1][ks], kf, s1);
            }
            S[0][jf] = s0;
            S[1][jf] = s1;
        }
        __builtin_amdgcn_s_setprio(0);

        // P = exp(S); per-lane partial l; bf16 P to per-wave LDS (A-layout)
#pragma unroll
        for (int rf = 0; rf < 2; ++rf)
#pragma unroll
            for (int r = 0; r < 4; ++r) {
                float p0 = __expf(S[rf][0][r]);
                float p1 = __expf(S[rf][1][r]);
                float p2 = __expf(S[rf][2][r]);
                float p3 = __expf(S[rf][3][r]);
                lsum[rf][r] += (p0 + p1) + (p2 + p3);
                int row = rf * 16 + quad * 4 + r;
                Pw[row * 76 + 0 * 16 + l15] = (bf16)p0;
                Pw[row * 76 + 1 * 16 + l15] = (bf16)p1;
                Pw[row * 76 + 2 * 16 + l15] = (bf16)p2;
                Pw[row * 76 + 3 * 16 + l15] = (bf16)p3;
            }

        // O += P V
        __builtin_amdgcn_s_setprio(1);
#pragma unroll
        for (int ks = 0; ks < 2; ++ks) {
            bf16x8 pf0 = *(const bf16x8*)(Pw + l15 * 76 + ks * 32 + quad * 8);
            bf16x8 pf1 = *(const bf16x8*)(Pw + (16 + l15) * 76 + ks * 32 + quad * 8);
#pragma unroll
            for (int cf = 0; cf < 8; ++cf) {
                bf16x8 vf = *(const bf16x8*)(Vt + (cf * 16 + l15) * 72 + ks * 32 + quad * 8);
                O[0][cf] = mfma16(pf0, vf, O[0][cf]);
                O[1][cf] = mfma16(pf1, vf, O[1][cf]);
            }
        }
        __builtin_amdgcn_s_setprio(0);
        __syncthreads();
    }

    // ---- combine group 1 partials into group 0 via (now dead) stage LDS ----
    float* scrO = (float*)smem;             // [64][256] f32 = 65536 B
    float* scrL = (float*)(smem + 71680);   // [8][256]  f32 =  8192 B
    bf16*  Yl   = (bf16*)(smem + 108544);   // [128][136] bf16 = 34816 B
    if (g == 1) {
#pragma unroll
        for (int rf = 0; rf < 2; ++rf)
#pragma unroll
            for (int cf = 0; cf < 8; ++cf)
#pragma unroll
                for (int r = 0; r < 4; ++r)
                    scrO[(rf * 32 + cf * 4 + r) * 256 + wg * 64 + lane] = O[rf][cf][r];
#pragma unroll
        for (int rf = 0; rf < 2; ++rf)
#pragma unroll
            for (int r = 0; r < 4; ++r)
                scrL[(rf * 4 + r) * 256 + wg * 64 + lane] = lsum[rf][r];
    }
    __syncthreads();
    if (g == 0) {
#pragma unroll
        for (int rf = 0; rf < 2; ++rf)
#pragma unroll
            for (int cf = 0; cf < 8; ++cf)
#pragma unroll
                for (int r = 0; r < 4; ++r)
                    O[rf][cf][r] += scrO[(rf * 32 + cf * 4 + r) * 256 + wg * 64 + lane];

        // one-time l reduction across the 16 lanes sharing each row
#pragma unroll
        for (int rf = 0; rf < 2; ++rf)
#pragma unroll
            for (int r = 0; r < 4; ++r) {
                float rs = lsum[rf][r] + scrL[(rf * 4 + r) * 256 + wg * 64 + lane];
                rs += __shfl_xor(rs, 1);
                rs += __shfl_xor(rs, 2);
                rs += __shfl_xor(rs, 4);
                rs += __shfl_xor(rs, 8);
                lsum[rf][r] = 1.f / rs;
            }

        // normalized bf16 Y-tile into LDS (row = px-local, col = ci)
#pragma unroll
        for (int rf = 0; rf < 2; ++rf)
#pragma unroll
            for (int cf = 0; cf < 8; ++cf)
#pragma unroll
                for (int r = 0; r < 4; ++r) {
                    int px = wg * 32 + rf * 16 + quad * 4 + r;
                    Yl[px * 136 + cf * 16 + l15] =
                        (bf16)(O[rf][cf][r] * lsum[rf][r]);
                }
    }
    __syncthreads();

    // ---- stage W_w -> Wl bf16 [256][136] over the dead staging region ----
    bf16* Wl = (bf16*)smem;
#pragma unroll
    for (int p = 0; p < 16; ++p) {
        int idx = p * 2048 + t * 4;          // 512 thr x 4 elems x 16 passes
        int o   = idx >> 7;
        int ci  = idx & 127;
        bf16x4 v;
        if (fp32) {
            floatx4 f4 = *(const floatx4*)((const float*)Ww + idx);
            v[0] = (bf16)f4[0]; v[1] = (bf16)f4[1];
            v[2] = (bf16)f4[2]; v[3] = (bf16)f4[3];
        } else {
            v = *(const bf16x4*)((const bf16*)Ww + idx);
        }
        *(bf16x4*)(&Wl[o * 136 + ci]) = v;
    }
    __syncthreads();

    // ---- out[o][px] = Ww @ Y + Wb + x : 8 waves = 4(o) x 2(px) of 64x64 ----
    {
        const int wm = w >> 1;   // o 64-block
        const int wn = w & 1;    // px 64-block
        floatx4 acc[4][4];
#pragma unroll
        for (int i = 0; i < 4; ++i)
#pragma unroll
            for (int j = 0; j < 4; ++j) acc[i][j] = (floatx4)0.f;

#pragma unroll
        for (int ks = 0; ks < 4; ++ks) {
            bf16x8 fa[4], fb[4];
#pragma unroll
            for (int i = 0; i < 4; ++i) {
                fa[i] = *(const bf16x8*)(&Wl[(wm * 64 + i * 16 + l15) * 136 + ks * 32 + quad * 8]);
                fb[i] = *(const bf16x8*)(&Yl[(wn * 64 + i * 16 + l15) * 136 + ks * 32 + quad * 8]);
            }
#pragma unroll
            for (int mi = 0; mi < 4; ++mi)
#pragma unroll
                for (int ni = 0; ni < 4; ++ni)
                    acc[mi][ni] = mfma16(fa[mi], fb[ni], acc[mi][ni]);
        }

#pragma unroll
        for (int mi = 0; mi < 4; ++mi)
#pragma unroll
            for (int ni = 0; ni < 4; ++ni)
#pragma unroll
                for (int r = 0; r < 4; ++r) {
                    int oo = wm * 64 + mi * 16 + quad * 4 + r;
                    int px = i0 + wn * 64 + ni * 16 + l15;
                    size_t idx = ((size_t)b * C_ + oo) * N_ + px;
                    float v = acc[mi][ni][r] + loadv(Wb, oo, fp32)
                            + loadv(x, idx, fp32);
                    if (fp32) ((float*)out)[idx] = v;
                    else      ((bf16*)out)[idx] = (bf16)v;
                }
    }
}

// ---------------------------------------------------------------------------
extern "C" void kernel_launch(void* const* d_in, const int* in_sizes, int n_in,
                              void* d_out, int out_size, void* d_ws, size_t ws_size,
                              hipStream_t stream) {
    const void* x    = d_in[0];
    const void* g_w  = d_in[1];
    const void* g_b  = d_in[2];
    const void* th_w = d_in[3];
    const void* th_b = d_in[4];
    const void* ph_w = d_in[5];
    const void* ph_b = d_in[6];
    const void* W_w  = d_in[7];
    const void* W_b  = d_in[8];

    const size_t plane = (size_t)B_ * N_ * CI_;
    bf16* T = (bf16*)d_ws;
    bf16* P = T + plane;
    bf16* G = P + plane;

    proj3_kernel<<<dim3(N_ / 128, B_), 512, 0, stream>>>(
        x, th_w, th_b, ph_w, ph_b, g_w, g_b, T, P, G);
    attn_kernel<<<dim3(N_ / 128 * B_), 512, 0, stream>>>(
        T, P, G, W_w, W_b, x, d_out);
}